// Round 1
// baseline (21101.425 us; speedup 1.0000x reference)
//
#include <hip/hip_runtime.h>

#define BATCH 64
#define TIN   49
#define NB    24
#define HID   384
#define SOUT  10
#define NGATE 5

// ---------------------------------------------------------------------------
// Prologue 1: temporal means -> initial h_prev / c_prev states
// hp_init / cp_init layout: [r][n][b][h]  (r in {0,1})
// ---------------------------------------------------------------------------
__global__ void init_means_kernel(const float* __restrict__ hid,
                                  const float* __restrict__ cel,
                                  const float* __restrict__ gt,
                                  float* __restrict__ hp_init,
                                  float* __restrict__ cp_init) {
    int idx = blockIdx.x * blockDim.x + threadIdx.x;   // over NB*BATCH*HID
    const int total = NB * BATCH * HID;
    if (idx >= total) return;
    int h = idx % HID;
    int b = (idx / HID) % BATCH;
    int n = idx / (HID * BATCH);
    const size_t frame_stride = (size_t)NB * HID;
    const float* ph = hid + ((size_t)b * TIN * NB + n) * HID + h;
    const float* pc = cel + ((size_t)b * TIN * NB + n) * HID + h;
    float sh = 0.f, sc = 0.f;
    for (int t = 0; t < TIN; ++t) {
        sh += ph[t * frame_stride];
        sc += pc[t * frame_stride];
    }
    float g = gt[((size_t)b * NB + n) * HID + h];
    hp_init[idx]         = sh / TIN;                  // r=0: mean over TIN
    hp_init[total + idx] = (g + sh) / (TIN + 1);      // r=1: mean over TIN+1 incl global_t
    cp_init[idx]         = sc / TIN;
    cp_init[total + idx] = sc / TIN;
}

// ---------------------------------------------------------------------------
// Prologue 2: spatial boundary (bone 0 left-neighbor) = mean over n of hp0
// bh/bc layout: [b][h]
// ---------------------------------------------------------------------------
__global__ void init_bounds_kernel(const float* __restrict__ hp_init,
                                   const float* __restrict__ cp_init,
                                   float* __restrict__ bh,
                                   float* __restrict__ bc) {
    int idx = blockIdx.x * blockDim.x + threadIdx.x;   // over BATCH*HID
    if (idx >= BATCH * HID) return;
    float sh = 0.f, sc = 0.f;
    for (int n = 0; n < NB; ++n) {
        sh += hp_init[(size_t)n * BATCH * HID + idx];
        sc += cp_init[(size_t)n * BATCH * HID + idx];
    }
    bh[idx] = sh / NB;
    bc[idx] = sc / NB;
}

// ---------------------------------------------------------------------------
// Wavefront cell kernel. One launch = one (diagonal d, rstep) pair.
// grid.x = HID/16 column tiles, grid.y = active cells on the diagonal.
// Block 256 threads: tx (0..15) -> one output column, ty (0..15) -> 4 batch rows.
// Each thread accumulates 5 gates x 4 rows over K = 3*384.
// State slots: h_sl/c_sl layout [parity][r][n][b][h], ping-pong on diagonal parity.
// ---------------------------------------------------------------------------
__global__ __launch_bounds__(256) void cell_kernel(
    int rstep, int d,
    const float* __restrict__ p,
    const float* __restrict__ U,
    const float* __restrict__ Wt,
    const float* __restrict__ Ws,
    const float* __restrict__ bias,
    const float* __restrict__ hp_init,
    const float* __restrict__ cp_init,
    const float* __restrict__ bh,
    const float* __restrict__ bc,
    float* __restrict__ h_sl,
    float* __restrict__ c_sl,
    float* __restrict__ out)
{
    const int cur = d & 1, prv = cur ^ 1;
    int n_lo = d - (SOUT - 1); if (n_lo < 0) n_lo = 0;
    const int n = n_lo + blockIdx.y;
    const int f = d - n;

    const int tx = threadIdx.x & 15;
    const int ty = threadIdx.x >> 4;
    const int k  = blockIdx.x * 16 + tx;      // output column (0..HID)

    const size_t npbh = (size_t)NB * BATCH * HID;

    auto slot = [&](float* base, int par, int r, int nn) -> float* {
        return base + ((size_t)(par * 2 + r) * NB + nn) * (size_t)BATCH * HID;
    };

    // resolve the three input vectors and the two cell-state vectors
    const float *xb, *htb, *hsb, *ctb, *csb;
    size_t xstr;
    if (rstep == 0) {
        xb   = p + ((size_t)f * NB + n) * HID;          // p[b,f,n,:]
        xstr = (size_t)SOUT * NB * HID;
        htb  = (f == 0) ? hp_init + (size_t)n * BATCH * HID : slot(h_sl, prv, 0, n);
        hsb  = (n == 0) ? bh : slot(h_sl, prv, 0, n - 1);
        ctb  = (f == 0) ? cp_init + (size_t)n * BATCH * HID : slot(c_sl, prv, 0, n);
        csb  = (n == 0) ? bc : slot(c_sl, prv, 0, n - 1);
    } else {
        xb   = slot(h_sl, cur, 0, n);                   // h0 of this cell (just computed)
        xstr = (size_t)HID;
        htb  = (f == 0) ? hp_init + npbh + (size_t)n * BATCH * HID : slot(h_sl, prv, 1, n);
        hsb  = (n == 0) ? bh : slot(h_sl, prv, 1, n - 1);
        ctb  = (f == 0) ? cp_init + npbh + (size_t)n * BATCH * HID : slot(c_sl, prv, 1, n);
        csb  = (n == 0) ? bc : slot(c_sl, prv, 1, n - 1);
    }

    float acc[NGATE][4];
    #pragma unroll
    for (int g = 0; g < NGATE; ++g)
        #pragma unroll
        for (int i = 0; i < 4; ++i) acc[g][i] = 0.f;

    __shared__ float xls[64][17];   // padded: avoids bank conflicts on reads

    const size_t wcell = ((size_t)rstep * NB + n) * NGATE * HID * HID;
    const float* wmats[3] = { U + wcell, Wt + wcell, Ws + wcell };
    const float* invec[3] = { xb, htb, hsb };
    const size_t instr_[3] = { xstr, (size_t)HID, (size_t)HID };

    for (int m = 0; m < 3; ++m) {
        const float* iv  = invec[m];
        const size_t is_ = instr_[m];
        const float* wm  = wmats[m];
        for (int h0 = 0; h0 < HID; h0 += 16) {
            __syncthreads();   // protect prior iteration's LDS reads
            {
                int lid = threadIdx.x;
                int row = lid >> 2;              // 0..63 batch row
                int hh0 = (lid & 3) << 2;        // 0,4,8,12
                const float4 v = *reinterpret_cast<const float4*>(
                    iv + (size_t)row * is_ + h0 + hh0);
                xls[row][hh0 + 0] = v.x;
                xls[row][hh0 + 1] = v.y;
                xls[row][hh0 + 2] = v.z;
                xls[row][hh0 + 3] = v.w;
            }
            __syncthreads();

            const float* wr = wm + (size_t)h0 * HID + k;
            #pragma unroll
            for (int hh = 0; hh < 16; ++hh) {
                float xr0 = xls[ty * 4 + 0][hh];
                float xr1 = xls[ty * 4 + 1][hh];
                float xr2 = xls[ty * 4 + 2][hh];
                float xr3 = xls[ty * 4 + 3][hh];
                #pragma unroll
                for (int g = 0; g < NGATE; ++g) {
                    float w = wr[(size_t)g * HID * HID + (size_t)hh * HID];
                    acc[g][0] += xr0 * w;
                    acc[g][1] += xr1 * w;
                    acc[g][2] += xr2 * w;
                    acc[g][3] += xr3 * w;
                }
            }
        }
    }

    // epilogue: bias + gates + cell update, write state slots (and output for r=1)
    const float* bb = bias + ((size_t)rstep * NB + n) * NGATE * HID;
    float bg[NGATE];
    #pragma unroll
    for (int g = 0; g < NGATE; ++g) bg[g] = bb[(size_t)g * HID + k];

    float* hdst = slot(h_sl, cur, rstep, n);
    float* cdst = slot(c_sl, cur, rstep, n);

    #pragma unroll
    for (int i = 0; i < 4; ++i) {
        int b = ty * 4 + i;
        float gi  = acc[0][i] + bg[0];
        float gfs = acc[1][i] + bg[1];
        float gft = acc[2][i] + bg[2];
        float go  = acc[3][i] + bg[3];
        float gc  = acc[4][i] + bg[4];
        float i_n = 1.f / (1.f + __expf(-gi));
        float f_s = 1.f / (1.f + __expf(-gfs));
        float f_t = 1.f / (1.f + __expf(-gft));
        float o_n = 1.f / (1.f + __expf(-go));
        float c_n = tanhf(gc);
        float ct  = ctb[(size_t)b * HID + k];
        float cs  = csb[(size_t)b * HID + k];
        float ch  = i_n * c_n + f_t * ct + f_s * cs;
        float hv  = o_n * tanhf(ch);
        hdst[(size_t)b * HID + k] = hv;
        cdst[(size_t)b * HID + k] = ch;
        if (rstep == 1) {
            size_t o = (((size_t)b * SOUT + f) * NB + n) * HID + k;
            out[o] = hv;
            out[(size_t)BATCH * SOUT * NB * HID + o] = ch;
        }
    }
}

// ---------------------------------------------------------------------------
extern "C" void kernel_launch(void* const* d_in, const int* in_sizes, int n_in,
                              void* d_out, int out_size, void* d_ws, size_t ws_size,
                              hipStream_t stream) {
    const float* hid  = (const float*)d_in[0];
    const float* cel  = (const float*)d_in[1];
    const float* gt   = (const float*)d_in[2];
    // d_in[3] = global_s_state: unused by the reference
    const float* p    = (const float*)d_in[4];
    const float* U    = (const float*)d_in[5];
    const float* Wt   = (const float*)d_in[6];
    const float* Ws   = (const float*)d_in[7];
    const float* bias = (const float*)d_in[8];
    float* out = (float*)d_out;

    float* ws = (float*)d_ws;
    const size_t npbh = (size_t)NB * BATCH * HID;
    float* hp_init = ws; ws += 2 * npbh;
    float* cp_init = ws; ws += 2 * npbh;
    float* bh      = ws; ws += (size_t)BATCH * HID;
    float* bc      = ws; ws += (size_t)BATCH * HID;
    float* h_sl    = ws; ws += 4 * npbh;   // [parity][r][n][b][h]
    float* c_sl    = ws; ws += 4 * npbh;

    init_means_kernel<<<(NB * BATCH * HID + 255) / 256, 256, 0, stream>>>(
        hid, cel, gt, hp_init, cp_init);
    init_bounds_kernel<<<(BATCH * HID + 255) / 256, 256, 0, stream>>>(
        hp_init, cp_init, bh, bc);

    for (int d = 0; d < SOUT + NB - 1; ++d) {
        int n_lo = d - (SOUT - 1); if (n_lo < 0) n_lo = 0;
        int n_hi = (d < NB - 1) ? d : NB - 1;
        int A = n_hi - n_lo + 1;
        dim3 grid(HID / 16, A);
        cell_kernel<<<grid, 256, 0, stream>>>(0, d, p, U, Wt, Ws, bias,
                                              hp_init, cp_init, bh, bc,
                                              h_sl, c_sl, out);
        cell_kernel<<<grid, 256, 0, stream>>>(1, d, p, U, Wt, Ws, bias,
                                              hp_init, cp_init, bh, bc,
                                              h_sl, c_sl, out);
    }
}

// Round 2
// 2046.671 us; speedup vs baseline: 10.3101x; 10.3101x over previous
//
#include <hip/hip_runtime.h>

#define BATCH 64
#define TIN   49
#define NB    24
#define HID   384
#define SOUT  10
#define NGATE 5

typedef __attribute__((ext_vector_type(4))) float f32x4;
typedef __attribute__((ext_vector_type(8))) short short8v;

__device__ __forceinline__ unsigned short f2bf(float f) {
    union { float f; unsigned u; } v; v.f = f;
    unsigned r = v.u + 0x7fffu + ((v.u >> 16) & 1u);   // round-nearest-even
    return (unsigned short)(r >> 16);
}
__device__ __forceinline__ float bf2f(unsigned short h) {
    union { unsigned u; float f; } v; v.u = ((unsigned)h) << 16; return v.f;
}

// ---------------------------------------------------------------------------
// Pack weights f32 [R,NB,G,H,H] (U,Wt,Ws) -> bf16 MFMA B-fragment order:
// wpack[(((cell*24 + t)*5 + g)*36 + kc)*64 + lane][8]
//   element j: B[k = kc*32 + (lane>>4)*8 + j][col = t*16 + (lane&15)]
//   k in [0,1152): m = k/384 selects U/Wt/Ws, kk = k%384.
// Reads: 16 consecutive lanes read 16 consecutive f32 (64B segments).
// Writes: thread writes 16B at tid*16 — fully coalesced.
// ---------------------------------------------------------------------------
__global__ void pack_w_kernel(const float* __restrict__ U,
                              const float* __restrict__ Wt,
                              const float* __restrict__ Ws,
                              unsigned short* __restrict__ wpack) {
    size_t tid = (size_t)blockIdx.x * 256 + threadIdx.x;   // 13,271,040 total
    int l = (int)(tid & 63); size_t q = tid >> 6;
    int kc = (int)(q % 36); q /= 36;
    int g  = (int)(q % NGATE); q /= NGATE;
    int t  = (int)(q % 24); q /= 24;
    int cell = (int)q;                                     // r*NB + n, 0..47
    int m = kc / 12;
    int kk0 = (kc % 12) * 32 + (l >> 4) * 8;
    int col = t * 16 + (l & 15);
    const float* W = (m == 0) ? U : (m == 1) ? Wt : Ws;
    const float* src = W + ((size_t)(cell * NGATE + g) * HID + kk0) * HID + col;
    unsigned short o[8];
#pragma unroll
    for (int j = 0; j < 8; ++j) o[j] = f2bf(src[(size_t)j * HID]);
    *(short8v*)(wpack + tid * 8) = *(const short8v*)o;
}

// p f32 [B][SOUT][NB][H] -> bf16 [SOUT][NB][B][H] (contiguous per cell)
__global__ void pack_p_kernel(const float* __restrict__ p,
                              unsigned short* __restrict__ pb) {
    size_t idx = (size_t)blockIdx.x * 256 + threadIdx.x;   // 5,898,240 total
    int h = (int)(idx % HID);
    size_t q = idx / HID;
    int b = (int)(q % BATCH); q /= BATCH;
    int n = (int)(q % NB); q /= NB;
    int f = (int)q;
    pb[idx] = f2bf(p[((size_t)(b * SOUT + f) * NB + n) * HID + h]);
}

// temporal means -> hp (bf16, GEMM input) + cp (f32, cell-state input)
// layout [r][n][b][h]
__global__ void init_means_kernel(const float* __restrict__ hid,
                                  const float* __restrict__ cel,
                                  const float* __restrict__ gt,
                                  unsigned short* __restrict__ hp_b,
                                  float* __restrict__ cp_f) {
    int idx = blockIdx.x * blockDim.x + threadIdx.x;       // NB*BATCH*HID
    const int total = NB * BATCH * HID;
    if (idx >= total) return;
    int h = idx % HID;
    int b = (idx / HID) % BATCH;
    int n = idx / (HID * BATCH);
    const size_t fs = (size_t)NB * HID;
    const float* ph = hid + ((size_t)b * TIN * NB + n) * HID + h;
    const float* pc = cel + ((size_t)b * TIN * NB + n) * HID + h;
    float sh = 0.f, sc = 0.f;
    for (int t = 0; t < TIN; ++t) { sh += ph[t * fs]; sc += pc[t * fs]; }
    float g = gt[((size_t)b * NB + n) * HID + h];
    hp_b[idx]         = f2bf(sh / TIN);
    hp_b[total + idx] = f2bf((g + sh) / (TIN + 1));
    cp_f[idx]         = sc / TIN;
    cp_f[total + idx] = sc / TIN;
}

// spatial boundary: mean over bones of the r=0 init states
__global__ void init_bounds_kernel(const unsigned short* __restrict__ hp_b,
                                   const float* __restrict__ cp_f,
                                   unsigned short* __restrict__ bh_b,
                                   float* __restrict__ bc_f) {
    int idx = blockIdx.x * blockDim.x + threadIdx.x;       // BATCH*HID
    if (idx >= BATCH * HID) return;
    float sh = 0.f, sc = 0.f;
    for (int n = 0; n < NB; ++n) {
        sh += bf2f(hp_b[(size_t)n * BATCH * HID + idx]);
        sc += cp_f[(size_t)n * BATCH * HID + idx];
    }
    bh_b[idx] = f2bf(sh / NB);
    bc_f[idx] = sc / NB;
}

// ---------------------------------------------------------------------------
// MFMA wavefront cell kernel. Block = 320 threads = 5 waves (one per gate).
// grid.x = 24 column tiles (16 cols each), grid.y = cells on the diagonal.
// Wave computes gates[64 batch rows x 16 cols] over K=1152 via 36 MFMA steps,
// barrier-free; one barrier before the fused LDS gate-exchange epilogue.
// States: h bf16 (GEMM operand), c f32 (exact arithmetic).
// ---------------------------------------------------------------------------
__global__ __launch_bounds__(320) void cell_kernel(
    int rstep, int d,
    const unsigned short* __restrict__ pb,
    const unsigned short* __restrict__ wpack,
    const float* __restrict__ bias,
    const unsigned short* __restrict__ hp_b,
    const float* __restrict__ cp_f,
    const unsigned short* __restrict__ bh_b,
    const float* __restrict__ bc_f,
    unsigned short* __restrict__ h_sl,   // [par][r][NB][64][384] bf16
    float* __restrict__ c_sl,            // same shape f32
    float* __restrict__ out)
{
    const int cur = d & 1, prv = cur ^ 1;
    int n_lo = d - (SOUT - 1); if (n_lo < 0) n_lo = 0;
    const int n = n_lo + blockIdx.y;
    const int f = d - n;
    const int t = blockIdx.x;
    const int wv = threadIdx.x >> 6;     // gate
    const int lane = threadIdx.x & 63;
    const int S = BATCH * HID;
    const int cell = rstep * NB + n;

    const unsigned short *xb, *htb, *hsb;
    const float *ctb, *csb;
    if (rstep == 0) {
        xb  = pb + (size_t)(f * NB + n) * S;
        htb = (f == 0) ? hp_b + (size_t)n * S
                       : h_sl + (size_t)((prv * 2 + 0) * NB + n) * S;
        hsb = (n == 0) ? bh_b
                       : h_sl + (size_t)((prv * 2 + 0) * NB + n - 1) * S;
        ctb = (f == 0) ? cp_f + (size_t)n * S
                       : c_sl + (size_t)((prv * 2 + 0) * NB + n) * S;
        csb = (n == 0) ? bc_f
                       : c_sl + (size_t)((prv * 2 + 0) * NB + n - 1) * S;
    } else {
        xb  = h_sl + (size_t)((cur * 2 + 0) * NB + n) * S;   // h0 of this cell
        htb = (f == 0) ? hp_b + (size_t)(NB + n) * S
                       : h_sl + (size_t)((prv * 2 + 1) * NB + n) * S;
        hsb = (n == 0) ? bh_b
                       : h_sl + (size_t)((prv * 2 + 1) * NB + n - 1) * S;
        ctb = (f == 0) ? cp_f + (size_t)(NB + n) * S
                       : c_sl + (size_t)((prv * 2 + 1) * NB + n) * S;
        csb = (n == 0) ? bc_f
                       : c_sl + (size_t)((prv * 2 + 1) * NB + n - 1) * S;
    }

    const short8v* wp = (const short8v*)wpack
        + (size_t)((cell * 24 + t) * NGATE + wv) * 36 * 64 + lane;

    const int rl = lane & 15;            // A row within 16-tile / B col
    const int kg = (lane >> 4) * 8;      // K sub-offset

    f32x4 acc0 = {0,0,0,0}, acc1 = {0,0,0,0}, acc2 = {0,0,0,0}, acc3 = {0,0,0,0};

    const unsigned short* srcs[3] = { xb, htb, hsb };
#pragma unroll
    for (int m = 0; m < 3; ++m) {
        const unsigned short* s = srcs[m] + (size_t)rl * HID + kg;
        const short8v* wpm = wp + (size_t)m * 12 * 64;
#pragma unroll 4
        for (int kk = 0; kk < 12; ++kk) {
            short8v bfr = wpm[(size_t)kk * 64];
            const unsigned short* sp = s + kk * 32;
            short8v a0 = *(const short8v*)(sp);
            short8v a1 = *(const short8v*)(sp + 16 * HID);
            short8v a2 = *(const short8v*)(sp + 32 * HID);
            short8v a3 = *(const short8v*)(sp + 48 * HID);
            acc0 = __builtin_amdgcn_mfma_f32_16x16x32_bf16(a0, bfr, acc0, 0, 0, 0);
            acc1 = __builtin_amdgcn_mfma_f32_16x16x32_bf16(a1, bfr, acc1, 0, 0, 0);
            acc2 = __builtin_amdgcn_mfma_f32_16x16x32_bf16(a2, bfr, acc2, 0, 0, 0);
            acc3 = __builtin_amdgcn_mfma_f32_16x16x32_bf16(a3, bfr, acc3, 0, 0, 0);
        }
    }

    __shared__ float gl[NGATE][64][17];
    {
        int rb = (lane >> 4) * 4;
#pragma unroll
        for (int i = 0; i < 4; ++i) {
            gl[wv][rb + i +  0][rl] = acc0[i];
            gl[wv][rb + i + 16][rl] = acc1[i];
            gl[wv][rb + i + 32][rl] = acc2[i];
            gl[wv][rb + i + 48][rl] = acc3[i];
        }
    }
    __syncthreads();

    if (threadIdx.x < 256) {
        int b  = threadIdx.x >> 2;
        int c0 = (threadIdx.x & 3) * 4;
        int colbase = t * 16 + c0;
        const float* bb = bias + (size_t)cell * NGATE * HID + colbase;

        size_t doff = (size_t)((cur * 2 + rstep) * NB + n) * S + (size_t)b * HID + colbase;
        unsigned short* hd = h_sl + doff;
        float* cd = c_sl + doff;

        float4 ct4 = *(const float4*)(ctb + (size_t)b * HID + colbase);
        float4 cs4 = *(const float4*)(csb + (size_t)b * HID + colbase);
        const float* ct_ = (const float*)&ct4;
        const float* cs_ = (const float*)&cs4;

        float hv4[4], ch4[4];
#pragma unroll
        for (int cc = 0; cc < 4; ++cc) {
            int c = c0 + cc;
            float gi  = gl[0][b][c] + bb[cc + 0 * HID];
            float gfs = gl[1][b][c] + bb[cc + 1 * HID];
            float gft = gl[2][b][c] + bb[cc + 2 * HID];
            float go  = gl[3][b][c] + bb[cc + 3 * HID];
            float gc  = gl[4][b][c] + bb[cc + 4 * HID];
            float i_n = 1.f / (1.f + __expf(-gi));
            float f_s = 1.f / (1.f + __expf(-gfs));
            float f_t = 1.f / (1.f + __expf(-gft));
            float o_n = 1.f / (1.f + __expf(-go));
            float c_n = tanhf(gc);
            float ch  = i_n * c_n + f_t * ct_[cc] + f_s * cs_[cc];
            float hv  = o_n * tanhf(ch);
            hv4[cc] = hv; ch4[cc] = ch;
            hd[cc] = f2bf(hv);
        }
        *(float4*)cd = make_float4(ch4[0], ch4[1], ch4[2], ch4[3]);
        if (rstep == 1) {
            size_t o = ((size_t)(b * SOUT + f) * NB + n) * HID + colbase;
            *(float4*)(out + o) = make_float4(hv4[0], hv4[1], hv4[2], hv4[3]);
            *(float4*)(out + (size_t)BATCH * SOUT * NB * HID + o)
                = make_float4(ch4[0], ch4[1], ch4[2], ch4[3]);
        }
    }
}

// ---------------------------------------------------------------------------
extern "C" void kernel_launch(void* const* d_in, const int* in_sizes, int n_in,
                              void* d_out, int out_size, void* d_ws, size_t ws_size,
                              hipStream_t stream) {
    const float* hid  = (const float*)d_in[0];
    const float* cel  = (const float*)d_in[1];
    const float* gt   = (const float*)d_in[2];
    // d_in[3] global_s_state: unused by the reference
    const float* p    = (const float*)d_in[4];
    const float* U    = (const float*)d_in[5];
    const float* Wt   = (const float*)d_in[6];
    const float* Ws   = (const float*)d_in[7];
    const float* bias = (const float*)d_in[8];
    float* out = (float*)d_out;

    char* cur_ = (char*)d_ws;
    auto carve = [&](size_t bytes) -> void* {
        void* r = cur_; cur_ += (bytes + 255) & ~(size_t)255; return r;
    };
    const size_t NPBH = (size_t)NB * BATCH * HID;
    unsigned short* wpack = (unsigned short*)carve((size_t)13271040 * 16); // 212 MB
    unsigned short* pb    = (unsigned short*)carve((size_t)SOUT * NB * BATCH * HID * 2);
    unsigned short* hp_b  = (unsigned short*)carve(2 * NPBH * 2);
    float*          cp_f  = (float*)carve(2 * NPBH * 4);
    unsigned short* bh_b  = (unsigned short*)carve((size_t)BATCH * HID * 2);
    float*          bc_f  = (float*)carve((size_t)BATCH * HID * 4);
    unsigned short* h_sl  = (unsigned short*)carve(4 * NPBH * 2);
    float*          c_sl  = (float*)carve(4 * NPBH * 4);

    pack_w_kernel<<<51840, 256, 0, stream>>>(U, Wt, Ws, wpack);
    pack_p_kernel<<<23040, 256, 0, stream>>>(p, pb);
    init_means_kernel<<<(NB * BATCH * HID + 255) / 256, 256, 0, stream>>>(
        hid, cel, gt, hp_b, cp_f);
    init_bounds_kernel<<<(BATCH * HID + 255) / 256, 256, 0, stream>>>(
        hp_b, cp_f, bh_b, bc_f);

    for (int d = 0; d < SOUT + NB - 1; ++d) {
        int n_lo = d - (SOUT - 1); if (n_lo < 0) n_lo = 0;
        int n_hi = (d < NB - 1) ? d : NB - 1;
        dim3 grid(24, n_hi - n_lo + 1);
        cell_kernel<<<grid, 320, 0, stream>>>(0, d, pb, wpack, bias,
                                              hp_b, cp_f, bh_b, bc_f,
                                              h_sl, c_sl, out);
        cell_kernel<<<grid, 320, 0, stream>>>(1, d, pb, wpack, bias,
                                              hp_b, cp_f, bh_b, bc_f,
                                              h_sl, c_sl, out);
    }
}

// Round 3
// 1739.762 us; speedup vs baseline: 12.1289x; 1.1764x over previous
//
#include <hip/hip_runtime.h>

#define BATCH 64
#define TIN   49
#define NB    24
#define HID   384
#define SOUT  10
#define NGATE 5

typedef __attribute__((ext_vector_type(4))) float f32x4;
typedef __attribute__((ext_vector_type(8))) short short8v;

__device__ __forceinline__ unsigned short f2bf(float f) {
    union { float f; unsigned u; } v; v.f = f;
    unsigned r = v.u + 0x7fffu + ((v.u >> 16) & 1u);   // round-nearest-even
    return (unsigned short)(r >> 16);
}
__device__ __forceinline__ float bf2f(unsigned short h) {
    union { unsigned u; float f; } v; v.u = ((unsigned)h) << 16; return v.f;
}

// ---------------------------------------------------------------------------
// Pack weights f32 [R,NB,G,H,H] (U,Wt,Ws) -> bf16 MFMA B-fragment order:
// wpack[(((cell*24 + t)*5 + g)*36 + kc)*64 + lane][8]
//   element j: B[k = kc*32 + (lane>>4)*8 + j][col = t*16 + (lane&15)]
//   k in [0,1152): m = k/384 selects U/Wt/Ws.
// ---------------------------------------------------------------------------
__global__ void pack_w_kernel(const float* __restrict__ U,
                              const float* __restrict__ Wt,
                              const float* __restrict__ Ws,
                              unsigned short* __restrict__ wpack) {
    size_t tid = (size_t)blockIdx.x * 256 + threadIdx.x;   // 13,271,040 total
    int l = (int)(tid & 63); size_t q = tid >> 6;
    int kc = (int)(q % 36); q /= 36;
    int g  = (int)(q % NGATE); q /= NGATE;
    int t  = (int)(q % 24); q /= 24;
    int cell = (int)q;                                     // r*NB + n, 0..47
    int m = kc / 12;
    int kk0 = (kc % 12) * 32 + (l >> 4) * 8;
    int col = t * 16 + (l & 15);
    const float* W = (m == 0) ? U : (m == 1) ? Wt : Ws;
    const float* src = W + ((size_t)(cell * NGATE + g) * HID + kk0) * HID + col;
    unsigned short o[8];
#pragma unroll
    for (int j = 0; j < 8; ++j) o[j] = f2bf(src[(size_t)j * HID]);
    *(short8v*)(wpack + tid * 8) = *(const short8v*)o;
}

// p f32 [B][SOUT][NB][H] -> bf16 [SOUT][NB][B][H] (contiguous per cell)
__global__ void pack_p_kernel(const float* __restrict__ p,
                              unsigned short* __restrict__ pb) {
    size_t idx = (size_t)blockIdx.x * 256 + threadIdx.x;   // 5,898,240 total
    int h = (int)(idx % HID);
    size_t q = idx / HID;
    int b = (int)(q % BATCH); q /= BATCH;
    int n = (int)(q % NB); q /= NB;
    int f = (int)q;
    pb[idx] = f2bf(p[((size_t)(b * SOUT + f) * NB + n) * HID + h]);
}

// temporal means -> hp (bf16) + cp (f32), layout [r][n][b][h]; float4-vectorized
__global__ void init_means_kernel(const float* __restrict__ hid,
                                  const float* __restrict__ cel,
                                  const float* __restrict__ gt,
                                  unsigned short* __restrict__ hp_b,
                                  float* __restrict__ cp_f) {
    int idx = blockIdx.x * blockDim.x + threadIdx.x;       // NB*BATCH*HID/4
    const int total4 = NB * BATCH * HID / 4;
    if (idx >= total4) return;
    const int H4 = HID / 4;
    int h = (idx % H4) * 4;
    int b = (idx / H4) % BATCH;
    int n = idx / (H4 * BATCH);
    const int fs4 = NB * HID / 4;
    const float4* ph = (const float4*)(hid + ((size_t)b * TIN * NB + n) * HID + h);
    const float4* pc = (const float4*)(cel + ((size_t)b * TIN * NB + n) * HID + h);
    float sh[4] = {0,0,0,0}, sc[4] = {0,0,0,0};
    for (int t = 0; t < TIN; ++t) {
        float4 vh = ph[(size_t)t * fs4];
        float4 vc = pc[(size_t)t * fs4];
        sh[0] += vh.x; sh[1] += vh.y; sh[2] += vh.z; sh[3] += vh.w;
        sc[0] += vc.x; sc[1] += vc.y; sc[2] += vc.z; sc[3] += vc.w;
    }
    float4 g4 = *(const float4*)(gt + ((size_t)b * NB + n) * HID + h);
    const float* g_ = (const float*)&g4;
    unsigned short o0[4], o1[4];
    float c0[4], c1[4];
#pragma unroll
    for (int j = 0; j < 4; ++j) {
        o0[j] = f2bf(sh[j] / TIN);
        o1[j] = f2bf((g_[j] + sh[j]) / (TIN + 1));
        c0[j] = sc[j] / TIN;
        c1[j] = sc[j] / TIN;
    }
    size_t base = (size_t)idx * 4;
    const size_t tot = (size_t)NB * BATCH * HID;
    *(uint2*)(hp_b + base)       = *(const uint2*)o0;
    *(uint2*)(hp_b + tot + base) = *(const uint2*)o1;
    *(float4*)(cp_f + base)       = make_float4(c0[0], c0[1], c0[2], c0[3]);
    *(float4*)(cp_f + tot + base) = make_float4(c1[0], c1[1], c1[2], c1[3]);
}

// spatial boundary: mean over bones of the r=0 init states
__global__ void init_bounds_kernel(const unsigned short* __restrict__ hp_b,
                                   const float* __restrict__ cp_f,
                                   unsigned short* __restrict__ bh_b,
                                   float* __restrict__ bc_f) {
    int idx = blockIdx.x * blockDim.x + threadIdx.x;       // BATCH*HID
    if (idx >= BATCH * HID) return;
    float sh = 0.f, sc = 0.f;
    for (int n = 0; n < NB; ++n) {
        sh += bf2f(hp_b[(size_t)n * BATCH * HID + idx]);
        sc += cp_f[(size_t)n * BATCH * HID + idx];
    }
    bh_b[idx] = f2bf(sh / NB);
    bc_f[idx] = sc / NB;
}

// ---------------------------------------------------------------------------
// Fused wavefront kernel: dispatch d covers r0 cells on diagonal d AND r1
// cells on diagonal d-1 (independent: all their deps come from dispatch d-1).
// Block = 640 threads = 10 waves: wave w -> gate = w%5, K-half = w/5.
// grid.x = 24 column tiles, grid.y = A0 (r0 cells) + A1 (r1 cells).
// Each wave: 18 MFMA steps (K=576 half), partials combined in LDS.
// ---------------------------------------------------------------------------
__global__ __launch_bounds__(640) void cell_fused_kernel(
    int d, int A0,
    const unsigned short* __restrict__ pb,
    const unsigned short* __restrict__ wpack,
    const float* __restrict__ bias,
    const unsigned short* __restrict__ hp_b,
    const float* __restrict__ cp_f,
    const unsigned short* __restrict__ bh_b,
    const float* __restrict__ bc_f,
    unsigned short* __restrict__ h_sl,   // [par][r][NB][64][384] bf16
    float* __restrict__ c_sl,            // same shape f32
    float* __restrict__ out)
{
    int y = blockIdx.y;
    int rstep, dg;
    if (y < A0) { rstep = 0; dg = d; }
    else        { rstep = 1; dg = d - 1; y -= A0; }
    int lo = dg - (SOUT - 1); if (lo < 0) lo = 0;
    const int n = lo + y;
    const int f = dg - n;
    const int cur = dg & 1, prv = cur ^ 1;
    const int t = blockIdx.x;
    const int wv   = threadIdx.x >> 6;
    const int gate = wv % NGATE;
    const int kh   = wv / NGATE;
    const int lane = threadIdx.x & 63;
    const int S = BATCH * HID;
    const int cell = rstep * NB + n;

    const unsigned short *xb, *htb, *hsb;
    const float *ctb, *csb;
    if (rstep == 0) {
        xb  = pb + (size_t)(f * NB + n) * S;
        htb = (f == 0) ? hp_b + (size_t)n * S
                       : h_sl + (size_t)((prv * 2 + 0) * NB + n) * S;
        hsb = (n == 0) ? bh_b
                       : h_sl + (size_t)((prv * 2 + 0) * NB + n - 1) * S;
        ctb = (f == 0) ? cp_f + (size_t)n * S
                       : c_sl + (size_t)((prv * 2 + 0) * NB + n) * S;
        csb = (n == 0) ? bc_f
                       : c_sl + (size_t)((prv * 2 + 0) * NB + n - 1) * S;
    } else {
        xb  = h_sl + (size_t)((cur * 2 + 0) * NB + n) * S;   // h0 of this cell
        htb = (f == 0) ? hp_b + (size_t)(NB + n) * S
                       : h_sl + (size_t)((prv * 2 + 1) * NB + n) * S;
        hsb = (n == 0) ? bh_b
                       : h_sl + (size_t)((prv * 2 + 1) * NB + n - 1) * S;
        ctb = (f == 0) ? cp_f + (size_t)(NB + n) * S
                       : c_sl + (size_t)((prv * 2 + 1) * NB + n) * S;
        csb = (n == 0) ? bc_f
                       : c_sl + (size_t)((prv * 2 + 1) * NB + n - 1) * S;
    }

    const short8v* wp = (const short8v*)wpack
        + (size_t)((cell * 24 + t) * NGATE + gate) * 36 * 64 + lane;

    const int rl = lane & 15;            // A row within 16-tile / B col
    const int kg = (lane >> 4) * 8;      // K sub-offset

    f32x4 acc0 = {0,0,0,0}, acc1 = {0,0,0,0}, acc2 = {0,0,0,0}, acc3 = {0,0,0,0};

    const unsigned short* s0 = xb  + (size_t)rl * HID + kg;
    const unsigned short* s1 = htb + (size_t)rl * HID + kg;
    const unsigned short* s2 = hsb + (size_t)rl * HID + kg;

    auto step = [&](const unsigned short* sp, int kcg) {
        short8v bfr = wp[(size_t)kcg * 64];
        short8v a0 = *(const short8v*)(sp);
        short8v a1 = *(const short8v*)(sp + 16 * HID);
        short8v a2 = *(const short8v*)(sp + 32 * HID);
        short8v a3 = *(const short8v*)(sp + 48 * HID);
        acc0 = __builtin_amdgcn_mfma_f32_16x16x32_bf16(a0, bfr, acc0, 0, 0, 0);
        acc1 = __builtin_amdgcn_mfma_f32_16x16x32_bf16(a1, bfr, acc1, 0, 0, 0);
        acc2 = __builtin_amdgcn_mfma_f32_16x16x32_bf16(a2, bfr, acc2, 0, 0, 0);
        acc3 = __builtin_amdgcn_mfma_f32_16x16x32_bf16(a3, bfr, acc3, 0, 0, 0);
    };

    if (kh == 0) {
#pragma unroll
        for (int kc = 0; kc < 12; ++kc) step(s0 + kc * 32, kc);
#pragma unroll
        for (int kc = 0; kc < 6; ++kc)  step(s1 + kc * 32, 12 + kc);
    } else {
#pragma unroll
        for (int kc = 6; kc < 12; ++kc) step(s1 + kc * 32, 12 + kc);
#pragma unroll
        for (int kc = 0; kc < 12; ++kc) step(s2 + kc * 32, 24 + kc);
    }

    __shared__ float gl[2][NGATE][64][17];
    {
        int rb = (lane >> 4) * 4;
#pragma unroll
        for (int i = 0; i < 4; ++i) {
            gl[kh][gate][rb + i +  0][rl] = acc0[i];
            gl[kh][gate][rb + i + 16][rl] = acc1[i];
            gl[kh][gate][rb + i + 32][rl] = acc2[i];
            gl[kh][gate][rb + i + 48][rl] = acc3[i];
        }
    }
    __syncthreads();

    if (threadIdx.x < 256) {
        int b  = threadIdx.x >> 2;
        int c0 = (threadIdx.x & 3) * 4;
        int colbase = t * 16 + c0;
        const float* bb = bias + (size_t)cell * NGATE * HID + colbase;

        size_t doff = (size_t)((cur * 2 + rstep) * NB + n) * S + (size_t)b * HID + colbase;
        unsigned short* hd = h_sl + doff;
        float* cd = c_sl + doff;

        float4 ct4 = *(const float4*)(ctb + (size_t)b * HID + colbase);
        float4 cs4 = *(const float4*)(csb + (size_t)b * HID + colbase);
        const float* ct_ = (const float*)&ct4;
        const float* cs_ = (const float*)&cs4;

        float hv4[4], ch4[4];
#pragma unroll
        for (int cc = 0; cc < 4; ++cc) {
            int c = c0 + cc;
            float gi  = gl[0][0][b][c] + gl[1][0][b][c] + bb[cc + 0 * HID];
            float gfs = gl[0][1][b][c] + gl[1][1][b][c] + bb[cc + 1 * HID];
            float gft = gl[0][2][b][c] + gl[1][2][b][c] + bb[cc + 2 * HID];
            float go  = gl[0][3][b][c] + gl[1][3][b][c] + bb[cc + 3 * HID];
            float gc  = gl[0][4][b][c] + gl[1][4][b][c] + bb[cc + 4 * HID];
            float i_n = 1.f / (1.f + __expf(-gi));
            float f_s = 1.f / (1.f + __expf(-gfs));
            float f_t = 1.f / (1.f + __expf(-gft));
            float o_n = 1.f / (1.f + __expf(-go));
            float c_n = tanhf(gc);
            float ch  = i_n * c_n + f_t * ct_[cc] + f_s * cs_[cc];
            float hv  = o_n * tanhf(ch);
            hv4[cc] = hv; ch4[cc] = ch;
            hd[cc] = f2bf(hv);
        }
        *(float4*)cd = make_float4(ch4[0], ch4[1], ch4[2], ch4[3]);
        if (rstep == 1) {
            size_t o = ((size_t)(b * SOUT + f) * NB + n) * HID + colbase;
            *(float4*)(out + o) = make_float4(hv4[0], hv4[1], hv4[2], hv4[3]);
            *(float4*)(out + (size_t)BATCH * SOUT * NB * HID + o)
                = make_float4(ch4[0], ch4[1], ch4[2], ch4[3]);
        }
    }
}

// ---------------------------------------------------------------------------
extern "C" void kernel_launch(void* const* d_in, const int* in_sizes, int n_in,
                              void* d_out, int out_size, void* d_ws, size_t ws_size,
                              hipStream_t stream) {
    const float* hid  = (const float*)d_in[0];
    const float* cel  = (const float*)d_in[1];
    const float* gt   = (const float*)d_in[2];
    // d_in[3] global_s_state: unused by the reference
    const float* p    = (const float*)d_in[4];
    const float* U    = (const float*)d_in[5];
    const float* Wt   = (const float*)d_in[6];
    const float* Ws   = (const float*)d_in[7];
    const float* bias = (const float*)d_in[8];
    float* out = (float*)d_out;

    char* cur_ = (char*)d_ws;
    auto carve = [&](size_t bytes) -> void* {
        void* r = cur_; cur_ += (bytes + 255) & ~(size_t)255; return r;
    };
    const size_t NPBH = (size_t)NB * BATCH * HID;
    unsigned short* wpack = (unsigned short*)carve((size_t)13271040 * 16); // 212 MB
    unsigned short* pb    = (unsigned short*)carve((size_t)SOUT * NB * BATCH * HID * 2);
    unsigned short* hp_b  = (unsigned short*)carve(2 * NPBH * 2);
    float*          cp_f  = (float*)carve(2 * NPBH * 4);
    unsigned short* bh_b  = (unsigned short*)carve((size_t)BATCH * HID * 2);
    float*          bc_f  = (float*)carve((size_t)BATCH * HID * 4);
    unsigned short* h_sl  = (unsigned short*)carve(4 * NPBH * 2);
    float*          c_sl  = (float*)carve(4 * NPBH * 4);

    pack_w_kernel<<<51840, 256, 0, stream>>>(U, Wt, Ws, wpack);
    pack_p_kernel<<<23040, 256, 0, stream>>>(p, pb);
    init_means_kernel<<<(NB * BATCH * HID / 4 + 255) / 256, 256, 0, stream>>>(
        hid, cel, gt, hp_b, cp_f);
    init_bounds_kernel<<<(BATCH * HID + 255) / 256, 256, 0, stream>>>(
        hp_b, cp_f, bh_b, bc_f);

    auto cnt = [](int dg) {
        int lo = dg - (SOUT - 1); if (lo < 0) lo = 0;
        int hi = (dg < NB - 1) ? dg : NB - 1;
        return hi - lo + 1;
    };
    for (int d = 0; d < SOUT + NB; ++d) {          // 34 dispatches
        int A0 = (d <= SOUT + NB - 2) ? cnt(d) : 0;
        int A1 = (d >= 1) ? cnt(d - 1) : 0;
        dim3 grid(24, A0 + A1);
        cell_fused_kernel<<<grid, 640, 0, stream>>>(d, A0, pb, wpack, bias,
                                                    hp_b, cp_f, bh_b, bc_f,
                                                    h_sl, c_sl, out);
    }
}

// Round 4
// 1682.504 us; speedup vs baseline: 12.5417x; 1.0340x over previous
//
#include <hip/hip_runtime.h>

#define BATCH 64
#define TIN   49
#define NB    24
#define HID   384
#define SOUT  10
#define NGATE 5

typedef __attribute__((ext_vector_type(4))) float f32x4;
typedef __attribute__((ext_vector_type(8))) short short8v;

__device__ __forceinline__ unsigned short f2bf(float f) {
    union { float f; unsigned u; } v; v.f = f;
    unsigned r = v.u + 0x7fffu + ((v.u >> 16) & 1u);   // round-nearest-even
    return (unsigned short)(r >> 16);
}
__device__ __forceinline__ float bf2f(unsigned short h) {
    union { unsigned u; float f; } v; v.u = ((unsigned)h) << 16; return v.f;
}

#define NW_BLK 51840
#define NP_BLK 23040
#define NM_BLK 576

// ---------------------------------------------------------------------------
// Fused prologue: pack_w + pack_p + init_means in one dispatch (independent
// work, split by blockIdx range) so their memory streams overlap.
// ---------------------------------------------------------------------------
__global__ __launch_bounds__(256) void prologue_kernel(
    const float* __restrict__ U, const float* __restrict__ Wt,
    const float* __restrict__ Ws, const float* __restrict__ p,
    const float* __restrict__ hid, const float* __restrict__ cel,
    const float* __restrict__ gt,
    unsigned short* __restrict__ wpack, unsigned short* __restrict__ pb,
    unsigned short* __restrict__ hp_b, float* __restrict__ cp_f)
{
    int bx = blockIdx.x;
    if (bx < NW_BLK) {
        // ---- pack weights -> bf16 MFMA B-fragment order:
        // wpack[(((cell*24+t)*5+g)*36+kc)*64 + lane][8]
        //   elem j: B[k=kc*32+(lane>>4)*8+j][col=t*16+(lane&15)], m=k/384 -> U/Wt/Ws
        size_t tid = (size_t)bx * 256 + threadIdx.x;       // 13,271,040
        int l = (int)(tid & 63); size_t q = tid >> 6;
        int kc = (int)(q % 36); q /= 36;
        int g  = (int)(q % NGATE); q /= NGATE;
        int t  = (int)(q % 24); q /= 24;
        int cell = (int)q;                                 // r*NB+n, 0..47
        int m = kc / 12;
        int kk0 = (kc % 12) * 32 + (l >> 4) * 8;
        int col = t * 16 + (l & 15);
        const float* W = (m == 0) ? U : (m == 1) ? Wt : Ws;
        const float* src = W + ((size_t)(cell * NGATE + g) * HID + kk0) * HID + col;
        unsigned short o[8];
#pragma unroll
        for (int j = 0; j < 8; ++j) o[j] = f2bf(src[(size_t)j * HID]);
        *(short8v*)(wpack + tid * 8) = *(const short8v*)o;
    } else if (bx < NW_BLK + NP_BLK) {
        // ---- p f32 [B][SOUT][NB][H] -> bf16 [SOUT][NB][B][H]
        size_t idx = (size_t)(bx - NW_BLK) * 256 + threadIdx.x;  // 5,898,240
        int h = (int)(idx % HID);
        size_t q = idx / HID;
        int b = (int)(q % BATCH); q /= BATCH;
        int n = (int)(q % NB); q /= NB;
        int f = (int)q;
        pb[idx] = f2bf(p[((size_t)(b * SOUT + f) * NB + n) * HID + h]);
    } else {
        // ---- temporal means -> hp (bf16) + cp (f32), layout [r][n][b][h]
        int idx = (bx - NW_BLK - NP_BLK) * 256 + threadIdx.x;    // 147,456
        const int total4 = NB * BATCH * HID / 4;
        if (idx >= total4) return;
        const int H4 = HID / 4;
        int h = (idx % H4) * 4;
        int b = (idx / H4) % BATCH;
        int n = idx / (H4 * BATCH);
        const int fs4 = NB * HID / 4;
        const float4* ph = (const float4*)(hid + ((size_t)b * TIN * NB + n) * HID + h);
        const float4* pc = (const float4*)(cel + ((size_t)b * TIN * NB + n) * HID + h);
        float sh[4] = {0,0,0,0}, sc[4] = {0,0,0,0};
        for (int t = 0; t < TIN; ++t) {
            float4 vh = ph[(size_t)t * fs4];
            float4 vc = pc[(size_t)t * fs4];
            sh[0] += vh.x; sh[1] += vh.y; sh[2] += vh.z; sh[3] += vh.w;
            sc[0] += vc.x; sc[1] += vc.y; sc[2] += vc.z; sc[3] += vc.w;
        }
        float4 g4 = *(const float4*)(gt + ((size_t)b * NB + n) * HID + h);
        const float* g_ = (const float*)&g4;
        unsigned short o0[4], o1[4];
        float c0[4];
#pragma unroll
        for (int j = 0; j < 4; ++j) {
            o0[j] = f2bf(sh[j] / TIN);
            o1[j] = f2bf((g_[j] + sh[j]) / (TIN + 1));
            c0[j] = sc[j] / TIN;
        }
        size_t base = (size_t)idx * 4;
        const size_t tot = (size_t)NB * BATCH * HID;
        *(uint2*)(hp_b + base)       = *(const uint2*)o0;
        *(uint2*)(hp_b + tot + base) = *(const uint2*)o1;
        *(float4*)(cp_f + base)       = make_float4(c0[0], c0[1], c0[2], c0[3]);
        *(float4*)(cp_f + tot + base) = make_float4(c0[0], c0[1], c0[2], c0[3]);
    }
}

// spatial boundary: mean over bones of the r=0 init states
__global__ void init_bounds_kernel(const unsigned short* __restrict__ hp_b,
                                   const float* __restrict__ cp_f,
                                   unsigned short* __restrict__ bh_b,
                                   float* __restrict__ bc_f) {
    int idx = blockIdx.x * blockDim.x + threadIdx.x;       // BATCH*HID
    if (idx >= BATCH * HID) return;
    float sh = 0.f, sc = 0.f;
    for (int n = 0; n < NB; ++n) {
        sh += bf2f(hp_b[(size_t)n * BATCH * HID + idx]);
        sc += cp_f[(size_t)n * BATCH * HID + idx];
    }
    bh_b[idx] = f2bf(sh / NB);
    bc_f[idx] = sc / NB;
}

// ---------------------------------------------------------------------------
// Fused wavefront kernel: dispatch d = r0 cells on diag d + r1 cells on diag
// d-1 (all deps come from dispatch d-1; parity ping-pong keeps planes apart).
// Block = 640 threads = 10 waves: wave w -> gate=w%5, K-half=w/5.
// K-loop is explicitly software-pipelined 4 deep (static slot indices) to
// keep ~20 global loads in flight per wave (every dispatch starts L2-cold).
// ---------------------------------------------------------------------------
__global__ __launch_bounds__(640) void cell_fused_kernel(
    int d, int A0,
    const unsigned short* __restrict__ pb,
    const unsigned short* __restrict__ wpack,
    const float* __restrict__ bias,
    const unsigned short* __restrict__ hp_b,
    const float* __restrict__ cp_f,
    const unsigned short* __restrict__ bh_b,
    const float* __restrict__ bc_f,
    unsigned short* __restrict__ h_sl,   // [par][r][NB][64][384] bf16
    float* __restrict__ c_sl,            // same shape f32
    float* __restrict__ out)
{
    int y = blockIdx.y;
    int rstep, dg;
    if (y < A0) { rstep = 0; dg = d; }
    else        { rstep = 1; dg = d - 1; y -= A0; }
    int lo = dg - (SOUT - 1); if (lo < 0) lo = 0;
    const int n = lo + y;
    const int f = dg - n;
    const int cur = dg & 1, prv = cur ^ 1;
    const int t = blockIdx.x;
    const int wv   = threadIdx.x >> 6;
    const int gate = wv % NGATE;
    const int kh   = wv / NGATE;
    const int lane = threadIdx.x & 63;
    const int S = BATCH * HID;
    const int cell = rstep * NB + n;

    const unsigned short *xb, *htb, *hsb;
    const float *ctb, *csb;
    if (rstep == 0) {
        xb  = pb + (size_t)(f * NB + n) * S;
        htb = (f == 0) ? hp_b + (size_t)n * S
                       : h_sl + (size_t)((prv * 2 + 0) * NB + n) * S;
        hsb = (n == 0) ? bh_b
                       : h_sl + (size_t)((prv * 2 + 0) * NB + n - 1) * S;
        ctb = (f == 0) ? cp_f + (size_t)n * S
                       : c_sl + (size_t)((prv * 2 + 0) * NB + n) * S;
        csb = (n == 0) ? bc_f
                       : c_sl + (size_t)((prv * 2 + 0) * NB + n - 1) * S;
    } else {
        xb  = h_sl + (size_t)((cur * 2 + 0) * NB + n) * S;   // h0 of this cell
        htb = (f == 0) ? hp_b + (size_t)(NB + n) * S
                       : h_sl + (size_t)((prv * 2 + 1) * NB + n) * S;
        hsb = (n == 0) ? bh_b
                       : h_sl + (size_t)((prv * 2 + 1) * NB + n - 1) * S;
        ctb = (f == 0) ? cp_f + (size_t)(NB + n) * S
                       : c_sl + (size_t)((prv * 2 + 1) * NB + n) * S;
        csb = (n == 0) ? bc_f
                       : c_sl + (size_t)((prv * 2 + 1) * NB + n - 1) * S;
    }

    // ---- epilogue operands issued early so their latency hides under MFMA
    float4 ct4, cs4;
    float4 bg[NGATE];
    int eb = threadIdx.x >> 2;             // batch row (tid<256)
    int ec0 = (threadIdx.x & 3) * 4;       // col quad
    int ecol = t * 16 + ec0;
    if (threadIdx.x < 256) {
        ct4 = *(const float4*)(ctb + (size_t)eb * HID + ecol);
        cs4 = *(const float4*)(csb + (size_t)eb * HID + ecol);
        const float* bbb = bias + (size_t)cell * NGATE * HID + ecol;
#pragma unroll
        for (int g = 0; g < NGATE; ++g) bg[g] = *(const float4*)(bbb + g * HID);
    }

    const short8v* wpB = (const short8v*)wpack
        + (size_t)((cell * 24 + t) * NGATE + gate) * 36 * 64
        + (size_t)kh * 18 * 64 + lane;

    const int rl = lane & 15;            // A row within 16-tile / B col
    const int kg = (lane >> 4) * 8;      // K sub-offset

    const unsigned short* s0 = xb  + (size_t)rl * HID + kg;
    const unsigned short* s1 = htb + (size_t)rl * HID + kg;
    const unsigned short* s2 = hsb + (size_t)rl * HID + kg;

    // A-source for pipeline step s (s folds to a constant under full unroll)
    auto addrA = [&](int s) -> const unsigned short* {
        if (kh == 0) return (s < 12) ? s0 + s * 32 : s1 + (s - 12) * 32;
        else         return (s < 6)  ? s1 + (s + 6) * 32 : s2 + (s - 6) * 32;
    };

    f32x4 acc0 = {0,0,0,0}, acc1 = {0,0,0,0}, acc2 = {0,0,0,0}, acc3 = {0,0,0,0};

    constexpr int PF = 4;
    short8v bb[PF];
    short8v aa[PF][4];

#pragma unroll
    for (int s = 0; s < PF; ++s) {
        bb[s] = wpB[(size_t)s * 64];
        const unsigned short* ap = addrA(s);
        aa[s][0] = *(const short8v*)(ap);
        aa[s][1] = *(const short8v*)(ap + 16 * HID);
        aa[s][2] = *(const short8v*)(ap + 32 * HID);
        aa[s][3] = *(const short8v*)(ap + 48 * HID);
    }
#pragma unroll
    for (int s = 0; s < 18; ++s) {
        const int slot = s & (PF - 1);
        short8v b_ = bb[slot];
        acc0 = __builtin_amdgcn_mfma_f32_16x16x32_bf16(aa[slot][0], b_, acc0, 0, 0, 0);
        acc1 = __builtin_amdgcn_mfma_f32_16x16x32_bf16(aa[slot][1], b_, acc1, 0, 0, 0);
        acc2 = __builtin_amdgcn_mfma_f32_16x16x32_bf16(aa[slot][2], b_, acc2, 0, 0, 0);
        acc3 = __builtin_amdgcn_mfma_f32_16x16x32_bf16(aa[slot][3], b_, acc3, 0, 0, 0);
        if (s + PF < 18) {
            const int nx = s + PF;
            bb[slot] = wpB[(size_t)nx * 64];
            const unsigned short* ap = addrA(nx);
            aa[slot][0] = *(const short8v*)(ap);
            aa[slot][1] = *(const short8v*)(ap + 16 * HID);
            aa[slot][2] = *(const short8v*)(ap + 32 * HID);
            aa[slot][3] = *(const short8v*)(ap + 48 * HID);
        }
    }

    __shared__ float gl[2][NGATE][64][17];
    {
        int rb = (lane >> 4) * 4;
#pragma unroll
        for (int i = 0; i < 4; ++i) {
            gl[kh][gate][rb + i +  0][rl] = acc0[i];
            gl[kh][gate][rb + i + 16][rl] = acc1[i];
            gl[kh][gate][rb + i + 32][rl] = acc2[i];
            gl[kh][gate][rb + i + 48][rl] = acc3[i];
        }
    }
    __syncthreads();

    if (threadIdx.x < 256) {
        const float* ct_ = (const float*)&ct4;
        const float* cs_ = (const float*)&cs4;
        size_t doff = (size_t)((cur * 2 + rstep) * NB + n) * S + (size_t)eb * HID + ecol;
        unsigned short* hd = h_sl + doff;
        float* cd = c_sl + doff;

        float hv4[4], ch4[4];
#pragma unroll
        for (int cc = 0; cc < 4; ++cc) {
            int c = ec0 + cc;
            float gi  = gl[0][0][eb][c] + gl[1][0][eb][c] + ((const float*)&bg[0])[cc];
            float gfs = gl[0][1][eb][c] + gl[1][1][eb][c] + ((const float*)&bg[1])[cc];
            float gft = gl[0][2][eb][c] + gl[1][2][eb][c] + ((const float*)&bg[2])[cc];
            float go  = gl[0][3][eb][c] + gl[1][3][eb][c] + ((const float*)&bg[3])[cc];
            float gc  = gl[0][4][eb][c] + gl[1][4][eb][c] + ((const float*)&bg[4])[cc];
            float i_n = 1.f / (1.f + __expf(-gi));
            float f_s = 1.f / (1.f + __expf(-gfs));
            float f_t = 1.f / (1.f + __expf(-gft));
            float o_n = 1.f / (1.f + __expf(-go));
            float c_n = tanhf(gc);
            float ch  = i_n * c_n + f_t * ct_[cc] + f_s * cs_[cc];
            float hv  = o_n * tanhf(ch);
            hv4[cc] = hv; ch4[cc] = ch;
            hd[cc] = f2bf(hv);
        }
        *(float4*)cd = make_float4(ch4[0], ch4[1], ch4[2], ch4[3]);
        if (rstep == 1) {
            size_t o = ((size_t)(eb * SOUT + f) * NB + n) * HID + ecol;
            *(float4*)(out + o) = make_float4(hv4[0], hv4[1], hv4[2], hv4[3]);
            *(float4*)(out + (size_t)BATCH * SOUT * NB * HID + o)
                = make_float4(ch4[0], ch4[1], ch4[2], ch4[3]);
        }
    }
}

// ---------------------------------------------------------------------------
extern "C" void kernel_launch(void* const* d_in, const int* in_sizes, int n_in,
                              void* d_out, int out_size, void* d_ws, size_t ws_size,
                              hipStream_t stream) {
    const float* hid  = (const float*)d_in[0];
    const float* cel  = (const float*)d_in[1];
    const float* gt   = (const float*)d_in[2];
    // d_in[3] global_s_state: unused by the reference
    const float* p    = (const float*)d_in[4];
    const float* U    = (const float*)d_in[5];
    const float* Wt   = (const float*)d_in[6];
    const float* Ws   = (const float*)d_in[7];
    const float* bias = (const float*)d_in[8];
    float* out = (float*)d_out;

    char* cur_ = (char*)d_ws;
    auto carve = [&](size_t bytes) -> void* {
        void* r = cur_; cur_ += (bytes + 255) & ~(size_t)255; return r;
    };
    const size_t NPBH = (size_t)NB * BATCH * HID;
    unsigned short* wpack = (unsigned short*)carve((size_t)13271040 * 16); // 212 MB
    unsigned short* pb    = (unsigned short*)carve((size_t)SOUT * NB * BATCH * HID * 2);
    unsigned short* hp_b  = (unsigned short*)carve(2 * NPBH * 2);
    float*          cp_f  = (float*)carve(2 * NPBH * 4);
    unsigned short* bh_b  = (unsigned short*)carve((size_t)BATCH * HID * 2);
    float*          bc_f  = (float*)carve((size_t)BATCH * HID * 4);
    unsigned short* h_sl  = (unsigned short*)carve(4 * NPBH * 2);
    float*          c_sl  = (float*)carve(4 * NPBH * 4);

    prologue_kernel<<<NW_BLK + NP_BLK + NM_BLK, 256, 0, stream>>>(
        U, Wt, Ws, p, hid, cel, gt, wpack, pb, hp_b, cp_f);
    init_bounds_kernel<<<(BATCH * HID + 255) / 256, 256, 0, stream>>>(
        hp_b, cp_f, bh_b, bc_f);

    auto cnt = [](int dg) {
        int lo = dg - (SOUT - 1); if (lo < 0) lo = 0;
        int hi = (dg < NB - 1) ? dg : NB - 1;
        return hi - lo + 1;
    };
    for (int d = 0; d < SOUT + NB; ++d) {          // 34 dispatches
        int A0 = (d <= SOUT + NB - 2) ? cnt(d) : 0;
        int A1 = (d >= 1) ? cnt(d - 1) : 0;
        dim3 grid(24, A0 + A1);
        cell_fused_kernel<<<grid, 640, 0, stream>>>(d, A0, pb, wpack, bias,
                                                    hp_b, cp_f, bh_b, bc_f,
                                                    h_sl, c_sl, out);
    }
}